// Round 1
// 287.225 us; speedup vs baseline: 1.0939x; 1.0939x over previous
//
#include <hip/hip_runtime.h>
#include <hip/hip_fp16.h>
#include <cstdint>
#include <cstddef>

#define NQQ  (144*144)        // 20736
#define SCALE 0.17677669529663687f

// ws layout in HALF elements. Base 57,378,816 halves = 114.76 MB.
// Optional bias-precompute region appended: +7,962,624 halves -> 130.7 MB.
#define AOH   0ull
#define X16H  0ull
#define QH    14155776ull
#define KH    28311552ull
#define VH    42467328ull
#define WTH   56623104ull      // 442368 halves (1152x384)
#define WOTH  57065472ull      // 147456 halves (384x384)
#define MASKH 57212928ull      // 165888 halves (8x144x144 fp16)
#define BIASH 57378816ull      // 3072 x 2592 fp16 precomputed bias (optional)
#define WS_NEED_BYTES ((BIASH + 3072ull * 2592ull) * 2ull)

typedef _Float16 half8  __attribute__((ext_vector_type(8)));
typedef _Float16 half4v __attribute__((ext_vector_type(4)));
typedef float    f32x4  __attribute__((ext_vector_type(4)));

// ---------------------------------------------------------------------------
// PREP: [0,13824) X fp32->fp16; [13824,13932) transpose w_qkv;
// [13932,13968) transpose w_out; [13968,14130) mask fp32->fp16;
// [14130,15426) OPTIONAL bias precompute: for (s_tile, 16-row chunk) read the
// gathered table rows ONCE coalesced (384 f32 each), LDS-transpose, store
// dense fp16 bias[bh][2592] so k_attn loads 5.2KB contiguously per block.
// ---------------------------------------------------------------------------
__launch_bounds__(256)
__global__ void k_prep(const float* __restrict__ X, _Float16* __restrict__ X16,
                       const float* __restrict__ Wq, _Float16* __restrict__ WqT,
                       const float* __restrict__ Wo, _Float16* __restrict__ WoT,
                       const float* __restrict__ M, _Float16* __restrict__ M16,
                       const float* __restrict__ table, const int* __restrict__ pidx,
                       _Float16* __restrict__ biasOut) {
    __shared__ __align__(16) char psm[13888];
    const int bid = blockIdx.x;
    const int t   = threadIdx.x;
    if (bid < 13824) {
        size_t i = (size_t)bid * 256 + t;
        float4 f = *(const float4*)&X[i * 4];
        _Float16 h[4] = {(_Float16)f.x, (_Float16)f.y, (_Float16)f.z, (_Float16)f.w};
        *(ushort4*)&X16[i * 4] = *(ushort4*)h;
        return;
    }
    if (bid >= 14130) {
        // ---- bias precompute: block = (s_tile, chunk of 16 i-rows) ----
        _Float16 (*sTb)[18] = (_Float16(*)[18])psm;   // 384 x 18 halves = 13824 B
        int* rowsL = (int*)(psm + 13824);             // 16 ints
        const int j      = bid - 14130;
        const int s_tile = j / 162;
        const int chunk  = j - s_tile * 162;
        const int i0     = chunk * 16;
        if (t < 16) rowsL[t] = pidx[8 * (i0 + t) + s_tile];
        __syncthreads();
#pragma unroll
        for (int rr = 0; rr < 16; ++rr) {
            int row = rowsL[rr];
            sTb[t][rr] = (_Float16)table[(size_t)row * 384 + t];
            if (t < 128) sTb[t + 256][rr] = (_Float16)table[(size_t)row * 384 + t + 256];
        }
        __syncthreads();
        unsigned int* ob = (unsigned int*)biasOut;    // dword view of fp16 pairs
#pragma unroll
        for (int v = t; v < 3072; v += 256) {
            int i1h = v >> 3, dw = v & 7;             // bh = s_tile*384 + i1h
            ob[(size_t)(s_tile * 384 + i1h) * 1296 + chunk * 8 + dw] =
                *(const unsigned int*)&sTb[i1h][dw * 2];
        }
        return;
    }
    if (bid >= 13968) {
        size_t i = (size_t)(bid - 13968) * 256 + t;
        float4 f = *(const float4*)&M[i * 4];
        _Float16 h[4] = {(_Float16)f.x, (_Float16)f.y, (_Float16)f.z, (_Float16)f.w};
        *(ushort4*)&M16[i * 4] = *(ushort4*)h;
        return;
    }
    _Float16 (*sT)[72] = (_Float16(*)[72])psm;        // 64 x 72 halves = 9216 B
    const float* W; _Float16* WT; int K, Cn, cb, kb;
    if (bid < 13932) {
        int j = bid - 13824;
        W = Wq; WT = WqT; K = 384; Cn = 1152;
        cb = (j % 18) * 64; kb = (j / 18) * 64;
    } else {
        int j = bid - 13932;
        W = Wo; WT = WoT; K = 384; Cn = 384;
        cb = (j % 6) * 64; kb = (j / 6) * 64;
    }
#pragma unroll
    for (int i = 0; i < 16; ++i) {
        int id = t + 256 * i;
        int kl = id >> 6, cl = id & 63;
        sT[cl][kl] = (_Float16)W[(size_t)(kb + kl) * Cn + cb + cl];
    }
    __syncthreads();
#pragma unroll
    for (int i = 0; i < 16; ++i) {
        int id = t + 256 * i;
        int cl = id >> 6, kl = id & 63;
        WT[(size_t)(cb + cl) * K + kb + kl] = sT[cl][kl];
    }
}

// ---------------------------------------------------------------------------
// K1: qkv = X16 @ WT^T (+bias, scale q) -> scatter fp16 [bh][n][d].
// ---------------------------------------------------------------------------
__launch_bounds__(256)
__global__ void k_qkv_gemm_mfma(const _Float16* __restrict__ X16,
                                const _Float16* __restrict__ WT,
                                const float* __restrict__ bq,
                                _Float16* __restrict__ ws16) {
    __shared__ _Float16 sA[128][40];
    __shared__ _Float16 sBT[128][40];
    const int t    = threadIdx.x;
    const int lane = t & 63;
    const int w    = t >> 6;
    const int quad = lane >> 4;
    const int l15  = lane & 15;
    const int r0   = blockIdx.x * 128, c0 = blockIdx.y * 128;
    const int wr   = (w >> 1) * 64, wc = (w & 1) * 64;

    f32x4 acc[4][4] = {};

    for (int kk = 0; kk < 384; kk += 32) {
#pragma unroll
        for (int i = 0; i < 2; ++i) {
            int id  = t + 256 * i;
            int row = id >> 2;
            int ko  = (id & 3) * 8;
            *(uint4*)&sA[row][ko]  = *(const uint4*)&X16[(size_t)(r0 + row) * 384 + kk + ko];
            *(uint4*)&sBT[row][ko] = *(const uint4*)&WT[(size_t)(c0 + row) * 384 + kk + ko];
        }
        __syncthreads();
        half8 a[4], b[4];
#pragma unroll
        for (int i = 0; i < 4; ++i) a[i] = *(const half8*)&sA[wr + 16 * i + l15][quad * 8];
#pragma unroll
        for (int j = 0; j < 4; ++j) b[j] = *(const half8*)&sBT[wc + 16 * j + l15][quad * 8];
#pragma unroll
        for (int i = 0; i < 4; ++i)
#pragma unroll
            for (int j = 0; j < 4; ++j)
                acc[i][j] = __builtin_amdgcn_mfma_f32_16x16x32_f16(a[i], b[j], acc[i][j], 0, 0, 0);
        __syncthreads();
    }

#pragma unroll
    for (int j = 0; j < 4; ++j) {
        int c  = c0 + wc + 16 * j + l15;
        int p  = c / 384;
        int hh = (c >> 5) % 12;
        int d0 = c & 31;
        float bias = bq[c];
        float sc   = (p == 0) ? SCALE : 1.0f;
        size_t base = (p == 0) ? QH : ((p == 1) ? KH : VH);
#pragma unroll
        for (int i = 0; i < 4; ++i) {
#pragma unroll
            for (int reg = 0; reg < 4; ++reg) {
                int r  = r0 + wr + 16 * i + quad * 4 + reg;
                int bw = r / 144;
                int n  = r - bw * 144;
                ws16[base + (((size_t)bw * 12 + hh) * 144 + n) * 32 + d0] =
                    (_Float16)((acc[i][j][reg] + bias) * sc);
            }
        }
    }
}

// ---------------------------------------------------------------------------
// K2: MFMA attention, S^T formulation — NO P round-trip through LDS.
// One (b,h) per block, 576 threads = 9 waves; wave w owns q-tile w.
// Bank-conflict fixes this rev:
//  - sBias row stride 144 -> 148 halves (dword stride 74, 74%32=10 -> 2-way).
//  - sVT column-chunk XOR swizzle m' = m ^ ((d>>3)<<3): transpose writes and
//    phase-4 ds_read_b128 both drop 4-way -> 2-way (free), 16B align kept.
//  - bias: contiguous 5.2KB load from precomputed table (no dependent
//    gathers in this kernel); gather fallback kept if ws too small.
// LDS: sK 11520 + sVT 10752 + sBias 5328 = 27600 B. ONE barrier.
// ---------------------------------------------------------------------------
__launch_bounds__(576)
__global__ void k_attn_fused_mfma(const _Float16* __restrict__ ws16,
                                  const _Float16* __restrict__ mask16,
                                  const float* __restrict__ table,
                                  const int* __restrict__ pidx,
                                  const _Float16* __restrict__ bias_pre,
                                  _Float16* __restrict__ AO) {
    __shared__ __align__(16) char smem[27616];
    _Float16 (*sK)[40]   = (_Float16(*)[40])(smem);             // 11520
    _Float16 (*sVT)[168] = (_Float16(*)[168])(smem + 11520);    // 10752
    _Float16* sBias      = (_Float16*)(smem + 22272);           // 18*148*2 = 5328

    const int bh = blockIdx.x;
    const int b  = bh / 12;
    const int h  = bh - b * 12;
    const int t  = threadIdx.x;
    const int w    = t >> 6;        // 0..8 : q-tile index
    const int lane = t & 63;
    const int quad = lane >> 4;
    const int l15  = lane & 15;

    const int s_tile = b >> 5;
    const int i1     = b & 31;

    // --- phase 1: loads ---
    const _Float16* qg = ws16 + QH + (size_t)bh * 4608;
    const _Float16* kg = ws16 + KH + (size_t)bh * 4608;
    const _Float16* vg = ws16 + VH + (size_t)bh * 4608;

    half8 aq = *(const half8*)&qg[(size_t)(16 * w + l15) * 32 + quad * 8];

    {   // K: one uint4 per thread (144 rows x 4 chunks = 576)
        int row = t >> 2, ko = (t & 3) * 8;
        *(uint4*)&sK[row][ko] = *(const uint4*)&kg[row * 32 + ko];
    }
    for (int i = t; i < 2304; i += 576) {          // V -> V^T (chunk-XOR swizzled)
        unsigned int u = ((const unsigned int*)vg)[i];
        int m  = i >> 4, d0 = (i & 15) * 2;
        int mp = m ^ ((d0 >> 3) << 3);             // d0 even: d0,d0+1 share d0>>3
        sVT[d0][mp]     = ((const _Float16*)&u)[0];
        sVT[d0 + 1][mp] = ((const _Float16*)&u)[1];
    }
    if (t < 512) {                                 // V^T zero-pad cols 144..159
        int d = t & 31, m = 144 + (t >> 5);
        sVT[d][m ^ ((d >> 3) << 3)] = (_Float16)0;
    }
    if (bias_pre) {                                // contiguous precomputed bias
        const _Float16* bg = bias_pre + (size_t)bh * 2592;
        for (int i2 = t; i2 < 648; i2 += 576) {
            uint2 wv = *(const uint2*)&bg[i2 * 4];
            int r18 = i2 / 36;
            int col = i2 * 4 - r18 * 144;
            *(uint2*)&sBias[r18 * 148 + col] = wv;
        }
    } else {                                       // fallback: gather (padded rows)
        for (int i = t; i < 2592; i += 576) {
            int row = pidx[8 * i + s_tile];
            int r18 = i / 144;
            sBias[r18 * 148 + (i - r18 * 144)] =
                (_Float16)table[(size_t)row * 384 + i1 * 12 + h];
        }
    }
    __syncthreads();   // the ONLY barrier

    // --- phase 2: T_j = S^T tiles = mfma(K_j, Q_w) ---
    f32x4 tj[9] = {};
#pragma unroll
    for (int j = 0; j < 9; ++j) {
        half8 bk = *(const half8*)&sK[16 * j + l15][quad * 8];
        tj[j] = __builtin_amdgcn_mfma_f32_16x16x32_f16(bk, aq, tj[j], 0, 0, 0);
    }

    // --- phase 3: bias + mask + softmax over each query column ---
    const int q    = 16 * w + l15;                 // this lane's query row
    const int nb18 = q % 18;
    const _Float16* mrow = mask16 + (size_t)(b & 7) * NQQ + (size_t)q * 144 + 4 * quad;
    uint2 mz[9];
#pragma unroll
    for (int j = 0; j < 9; ++j) mz[j] = *(const uint2*)&mrow[16 * j];
#pragma unroll
    for (int j = 0; j < 9; ++j) {
        uint2 bz = *(const uint2*)&sBias[nb18 * 148 + 16 * j + 4 * quad];
        const _Float16* bb = (const _Float16*)&bz;
        const _Float16* mm = (const _Float16*)&mz[j];
#pragma unroll
        for (int reg = 0; reg < 4; ++reg)
            tj[j][reg] += (float)bb[reg] + (float)mm[reg];
    }
    float rmax = tj[0][0];
#pragma unroll
    for (int j = 0; j < 9; ++j)
#pragma unroll
        for (int reg = 0; reg < 4; ++reg) rmax = fmaxf(rmax, tj[j][reg]);
    rmax = fmaxf(rmax, __shfl_xor(rmax, 16));
    rmax = fmaxf(rmax, __shfl_xor(rmax, 32));
    float rsum = 0.0f;
#pragma unroll
    for (int j = 0; j < 9; ++j)
#pragma unroll
        for (int reg = 0; reg < 4; ++reg) {
            tj[j][reg] = __expf(tj[j][reg] - rmax);
            rsum += tj[j][reg];
        }
    rsum += __shfl_xor(rsum, 16);
    rsum += __shfl_xor(rsum, 32);
    const float inv = 1.0f / rsum;

    // pack P^T rows (scaled) to fp16 pairs; index 9 = zero pad (keys 144..159)
    unsigned int pkA[10], pkB[10];
    pkA[9] = 0u; pkB[9] = 0u;
#pragma unroll
    for (int j = 0; j < 9; ++j) {
        auto a2 = __builtin_amdgcn_cvt_pkrtz(tj[j][0] * inv, tj[j][1] * inv);
        auto b2 = __builtin_amdgcn_cvt_pkrtz(tj[j][2] * inv, tj[j][3] * inv);
        pkA[j] = *(unsigned int*)&a2;
        pkB[j] = *(unsigned int*)&b2;
    }

    // --- phase 4: O^T = V^T @ P^T ; P^T B-frags via cross-lane shuffles ---
    const int src_lo = 32 * (quad & 1) + l15;
    const int src_hi = src_lo + 16;
    const bool selhi = (quad >> 1) != 0;
    f32x4 o[2] = {};
#pragma unroll
    for (int kt = 0; kt < 5; ++kt) {
        const int j0 = 2 * kt, j1 = 2 * kt + 1;
        unsigned int a0l = __shfl((int)pkA[j0], src_lo);
        unsigned int a1l = __shfl((int)pkA[j1], src_lo);
        unsigned int b0l = __shfl((int)pkB[j0], src_lo);
        unsigned int b1l = __shfl((int)pkB[j1], src_lo);
        unsigned int a0h = __shfl((int)pkA[j0], src_hi);
        unsigned int a1h = __shfl((int)pkA[j1], src_hi);
        unsigned int b0h = __shfl((int)pkB[j0], src_hi);
        unsigned int b1h = __shfl((int)pkB[j1], src_hi);
        union { uint4 u4; half8 h8; } bp;
        bp.u4.x = selhi ? a1l : a0l;
        bp.u4.y = selhi ? b1l : b0l;
        bp.u4.z = selhi ? a1h : a0h;
        bp.u4.w = selhi ? b1h : b0h;
#pragma unroll
        for (int dt = 0; dt < 2; ++dt) {
            const int vrow = dt * 16 + l15;
            half8 av = *(const half8*)&sVT[vrow][(kt * 32 + quad * 8) ^ ((vrow >> 3) << 3)];
            o[dt] = __builtin_amdgcn_mfma_f32_16x16x32_f16(av, bp.h8, o[dt], 0, 0, 0);
        }
    }

    // --- stores: O^T[d][q] -> AO[b][q][h*32+d] ---
#pragma unroll
    for (int dt = 0; dt < 2; ++dt) {
        int d = dt * 16 + quad * 4;
        half4v hv;
#pragma unroll
        for (int reg = 0; reg < 4; ++reg) hv[reg] = (_Float16)o[dt][reg];
        *(half4v*)&AO[((size_t)b * 144 + q) * 384 + h * 32 + d] = hv;
    }
}

// ---------------------------------------------------------------------------
// K3: out = AO @ WoT^T + b_out. fp32 output.
// ---------------------------------------------------------------------------
__launch_bounds__(256)
__global__ void k_out_gemm_mfma(const _Float16* __restrict__ A16,
                                const _Float16* __restrict__ WoT,
                                const float* __restrict__ bo,
                                float* __restrict__ out) {
    __shared__ _Float16 sA[128][40];
    __shared__ _Float16 sBT[128][40];
    const int t    = threadIdx.x;
    const int lane = t & 63;
    const int w    = t >> 6;
    const int quad = lane >> 4;
    const int l15  = lane & 15;
    const int r0   = blockIdx.x * 128, c0 = blockIdx.y * 128;
    const int wr   = (w >> 1) * 64, wc = (w & 1) * 64;

    f32x4 acc[4][4] = {};

    for (int kk = 0; kk < 384; kk += 32) {
#pragma unroll
        for (int i = 0; i < 2; ++i) {
            int id  = t + 256 * i;
            int row = id >> 2;
            int ko  = (id & 3) * 8;
            *(uint4*)&sA[row][ko]  = *(const uint4*)&A16[(size_t)(r0 + row) * 384 + kk + ko];
            *(uint4*)&sBT[row][ko] = *(const uint4*)&WoT[(size_t)(c0 + row) * 384 + kk + ko];
        }
        __syncthreads();
        half8 a[4], b[4];
#pragma unroll
        for (int i = 0; i < 4; ++i) a[i] = *(const half8*)&sA[wr + 16 * i + l15][quad * 8];
#pragma unroll
        for (int j = 0; j < 4; ++j) b[j] = *(const half8*)&sBT[wc + 16 * j + l15][quad * 8];
#pragma unroll
        for (int i = 0; i < 4; ++i)
#pragma unroll
            for (int j = 0; j < 4; ++j)
                acc[i][j] = __builtin_amdgcn_mfma_f32_16x16x32_f16(a[i], b[j], acc[i][j], 0, 0, 0);
        __syncthreads();
    }

#pragma unroll
    for (int j = 0; j < 4; ++j) {
        int c = c0 + wc + 16 * j + l15;
        float bias = bo[c];
#pragma unroll
        for (int i = 0; i < 4; ++i) {
#pragma unroll
            for (int reg = 0; reg < 4; ++reg) {
                int r = r0 + wr + 16 * i + quad * 4 + reg;
                out[(size_t)r * 384 + c] = acc[i][j][reg] + bias;
            }
        }
    }
}

// ---------------------------------------------------------------------------
extern "C" void kernel_launch(void* const* d_in, const int* in_sizes, int n_in,
                              void* d_out, int out_size, void* d_ws, size_t ws_size,
                              hipStream_t stream) {
    const float* x      = (const float*)d_in[0];
    const float* mask   = (const float*)d_in[1];
    const float* w_qkv  = (const float*)d_in[2];
    const float* b_qkv  = (const float*)d_in[3];
    const float* w_out  = (const float*)d_in[4];
    const float* b_out  = (const float*)d_in[5];
    const float* table  = (const float*)d_in[6];
    const int*   pidx   = (const int*)d_in[7];
    float* out = (float*)d_out;
    _Float16* ws16 = (_Float16*)d_ws;

    const bool pre = ws_size >= (size_t)WS_NEED_BYTES;
    _Float16* bias16 = pre ? (ws16 + BIASH) : (_Float16*)nullptr;

    hipLaunchKernelGGL(k_prep,          dim3(pre ? 15426 : 14130), dim3(256), 0, stream,
                       x, ws16 + X16H, w_qkv, ws16 + WTH, w_out, ws16 + WOTH,
                       mask, ws16 + MASKH, table, pidx, bias16);
    hipLaunchKernelGGL(k_qkv_gemm_mfma, dim3(288, 9), dim3(256), 0, stream,
                       ws16 + X16H, ws16 + WTH, b_qkv, ws16);
    hipLaunchKernelGGL(k_attn_fused_mfma, dim3(3072), dim3(576), 0, stream,
                       ws16, ws16 + MASKH, table, pidx, bias16, ws16 + AOH);
    hipLaunchKernelGGL(k_out_gemm_mfma, dim3(288, 3), dim3(256), 0, stream,
                       ws16 + AOH, ws16 + WOTH, b_out, out);
}

// Round 3
// 257.861 us; speedup vs baseline: 1.2185x; 1.1139x over previous
//
#include <hip/hip_runtime.h>
#include <hip/hip_fp16.h>
#include <cstdint>
#include <cstddef>

#define NQQ  (144*144)        // 20736
#define SCALE 0.17677669529663687f

// ws layout in HALF elements. Base 57,378,816 halves = 114.76 MB.
// Optional bias-precompute region appended: +7,962,624 halves -> 130.7 MB.
#define AOH   0ull
#define X16H  0ull
#define QH    14155776ull
#define KH    28311552ull
#define VH    42467328ull
#define WTH   56623104ull      // 442368 halves (1152x384)
#define WOTH  57065472ull      // 147456 halves (384x384)
#define MASKH 57212928ull      // 165888 halves (8x144x144 fp16)
#define BIASH 57378816ull      // 3072 x 2592 fp16 precomputed bias (optional)
#define WS_NEED_BYTES ((BIASH + 3072ull * 2592ull) * 2ull)

typedef _Float16 half8  __attribute__((ext_vector_type(8)));
typedef _Float16 half4v __attribute__((ext_vector_type(4)));
typedef float    f32x4  __attribute__((ext_vector_type(4)));

typedef __attribute__((address_space(1))) const unsigned int guint;
typedef __attribute__((address_space(3))) unsigned int luint;
#define GLD16(g, l) __builtin_amdgcn_global_load_lds((guint*)(g), (luint*)(l), 16, 0, 0)

// ---------------------------------------------------------------------------
// PREP: [0,13824) X fp32->fp16; [13824,13932) transpose w_qkv;
// [13932,13968) transpose w_out; [13968,14130) mask fp32->fp16;
// [14130,15426) OPTIONAL bias precompute: for (s_tile, 16-row chunk) read the
// gathered table rows ONCE coalesced (384 f32 each), LDS-transpose, store
// dense fp16 bias[bh][2592] so k_attn loads 5.2KB contiguously per block.
// ---------------------------------------------------------------------------
__launch_bounds__(256)
__global__ void k_prep(const float* __restrict__ X, _Float16* __restrict__ X16,
                       const float* __restrict__ Wq, _Float16* __restrict__ WqT,
                       const float* __restrict__ Wo, _Float16* __restrict__ WoT,
                       const float* __restrict__ M, _Float16* __restrict__ M16,
                       const float* __restrict__ table, const int* __restrict__ pidx,
                       _Float16* __restrict__ biasOut) {
    __shared__ __align__(16) char psm[13888];
    const int bid = blockIdx.x;
    const int t   = threadIdx.x;
    if (bid < 13824) {
        size_t i = (size_t)bid * 256 + t;
        float4 f = *(const float4*)&X[i * 4];
        _Float16 h[4] = {(_Float16)f.x, (_Float16)f.y, (_Float16)f.z, (_Float16)f.w};
        *(ushort4*)&X16[i * 4] = *(ushort4*)h;
        return;
    }
    if (bid >= 14130) {
        // ---- bias precompute: block = (s_tile, chunk of 16 i-rows) ----
        _Float16 (*sTb)[18] = (_Float16(*)[18])psm;   // 384 x 18 halves = 13824 B
        int* rowsL = (int*)(psm + 13824);             // 16 ints
        const int j      = bid - 14130;
        const int s_tile = j / 162;
        const int chunk  = j - s_tile * 162;
        const int i0     = chunk * 16;
        if (t < 16) rowsL[t] = pidx[8 * (i0 + t) + s_tile];
        __syncthreads();
#pragma unroll
        for (int rr = 0; rr < 16; ++rr) {
            int row = rowsL[rr];
            sTb[t][rr] = (_Float16)table[(size_t)row * 384 + t];
            if (t < 128) sTb[t + 256][rr] = (_Float16)table[(size_t)row * 384 + t + 256];
        }
        __syncthreads();
        unsigned int* ob = (unsigned int*)biasOut;    // dword view of fp16 pairs
#pragma unroll
        for (int v = t; v < 3072; v += 256) {
            int i1h = v >> 3, dw = v & 7;             // bh = s_tile*384 + i1h
            ob[(size_t)(s_tile * 384 + i1h) * 1296 + chunk * 8 + dw] =
                *(const unsigned int*)&sTb[i1h][dw * 2];
        }
        return;
    }
    if (bid >= 13968) {
        size_t i = (size_t)(bid - 13968) * 256 + t;
        float4 f = *(const float4*)&M[i * 4];
        _Float16 h[4] = {(_Float16)f.x, (_Float16)f.y, (_Float16)f.z, (_Float16)f.w};
        *(ushort4*)&M16[i * 4] = *(ushort4*)h;
        return;
    }
    _Float16 (*sT)[72] = (_Float16(*)[72])psm;        // 64 x 72 halves = 9216 B
    const float* W; _Float16* WT; int K, Cn, cb, kb;
    if (bid < 13932) {
        int j = bid - 13824;
        W = Wq; WT = WqT; K = 384; Cn = 1152;
        cb = (j % 18) * 64; kb = (j / 18) * 64;
    } else {
        int j = bid - 13932;
        W = Wo; WT = WoT; K = 384; Cn = 384;
        cb = (j % 6) * 64; kb = (j / 6) * 64;
    }
#pragma unroll
    for (int i = 0; i < 16; ++i) {
        int id = t + 256 * i;
        int kl = id >> 6, cl = id & 63;
        sT[cl][kl] = (_Float16)W[(size_t)(kb + kl) * Cn + cb + cl];
    }
    __syncthreads();
#pragma unroll
    for (int i = 0; i < 16; ++i) {
        int id = t + 256 * i;
        int cl = id >> 6, kl = id & 63;
        WT[(size_t)(cb + cl) * K + kb + kl] = sT[cl][kl];
    }
}

// ---------------------------------------------------------------------------
// K1: qkv = X16 @ WT^T (+bias, scale q) -> scatter fp16 [bh][n][d].
// v2: global_load_lds width-16 staging into linear [128][64] LDS with
// read-side XOR swizzle chunk^=(row&7) applied by PRE-SWIZZLING the per-lane
// global source (rule #21). Conflict-free ds_read_b128; zero ds_writes.
// 1D grid, bijective XCD-chunked swizzle, col-tile fastest -> A-panel L2 reuse.
// ---------------------------------------------------------------------------
__launch_bounds__(256)
__global__ void k_qkv_gemm_mfma(const _Float16* __restrict__ X16,
                                const _Float16* __restrict__ WT,
                                const float* __restrict__ bq,
                                _Float16* __restrict__ ws16) {
    __shared__ __align__(16) _Float16 sA[128 * 64];
    __shared__ __align__(16) _Float16 sB[128 * 64];
    const int t    = threadIdx.x;
    const int lane = t & 63;
    const int w    = t >> 6;
    const int quad = lane >> 4;
    const int l15  = lane & 15;
    // bijective XCD swizzle: 2592 = 8 * 324; col-tile fastest within chunk
    const int bid = blockIdx.x;
    const int wg  = (bid & 7) * 324 + (bid >> 3);
    const int cy  = wg % 9, rx = wg / 9;
    const int r0  = rx * 128, c0 = cy * 128;
    const int wr  = (w >> 1) * 64, wc = (w & 1) * 64;

    // staging: lane t fills dest row j*32+(t>>3), chunk t&7 of each 4KB slice
    const int drow = t >> 3;
    const int schk = (t & 7) ^ (drow & 7);   // inverse-swizzled source chunk
    const _Float16* gA = &X16[(size_t)(r0 + drow) * 384 + schk * 8];
    const _Float16* gB = &WT [(size_t)(c0 + drow) * 384 + schk * 8];
    char* lA = (char*)sA + t * 16;
    char* lB = (char*)sB + t * 16;

    // read-side bases
    const int x7 = l15 & 7;
    const char* rA = (const char*)sA + (wr + l15) * 128;
    const char* rB = (const char*)sB + (wc + l15) * 128;

    f32x4 acc[4][4] = {};

    for (int kk = 0; kk < 384; kk += 64) {
#pragma unroll
        for (int j = 0; j < 4; ++j) {
            GLD16(gA + (size_t)j * 12288 + kk, lA + j * 4096);
            GLD16(gB + (size_t)j * 12288 + kk, lB + j * 4096);
        }
        __syncthreads();
#pragma unroll
        for (int s = 0; s < 2; ++s) {
            const int ca = (((s * 4 + quad) ^ x7) << 4);
            half8 a[4], b[4];
#pragma unroll
            for (int i = 0; i < 4; ++i) a[i] = *(const half8*)(rA + i * 2048 + ca);
#pragma unroll
            for (int j = 0; j < 4; ++j) b[j] = *(const half8*)(rB + j * 2048 + ca);
#pragma unroll
            for (int i = 0; i < 4; ++i)
#pragma unroll
                for (int j = 0; j < 4; ++j)
                    acc[i][j] = __builtin_amdgcn_mfma_f32_16x16x32_f16(a[i], b[j], acc[i][j], 0, 0, 0);
        }
        __syncthreads();
    }

#pragma unroll
    for (int j = 0; j < 4; ++j) {
        int c  = c0 + wc + 16 * j + l15;
        int p  = c / 384;
        int hh = (c >> 5) % 12;
        int d0 = c & 31;
        float bias = bq[c];
        float sc   = (p == 0) ? SCALE : 1.0f;
        size_t base = (p == 0) ? QH : ((p == 1) ? KH : VH);
#pragma unroll
        for (int i = 0; i < 4; ++i) {
#pragma unroll
            for (int reg = 0; reg < 4; ++reg) {
                int r  = r0 + wr + 16 * i + quad * 4 + reg;
                int bw = r / 144;
                int n  = r - bw * 144;
                ws16[base + (((size_t)bw * 12 + hh) * 144 + n) * 32 + d0] =
                    (_Float16)((acc[i][j][reg] + bias) * sc);
            }
        }
    }
}

// ---------------------------------------------------------------------------
// K2: MFMA attention, S^T formulation — NO P round-trip through LDS.
// One (b,h) per block, 576 threads = 9 waves; wave w owns q-tile w.
// sBias stride 148 (2-way), sVT chunk-XOR swizzle (2-way), precomputed bias.
// LDS: sK 11520 + sVT 10752 + sBias 5328 = 27600 B. ONE barrier.
// ---------------------------------------------------------------------------
__launch_bounds__(576)
__global__ void k_attn_fused_mfma(const _Float16* __restrict__ ws16,
                                  const _Float16* __restrict__ mask16,
                                  const float* __restrict__ table,
                                  const int* __restrict__ pidx,
                                  const _Float16* __restrict__ bias_pre,
                                  _Float16* __restrict__ AO) {
    __shared__ __align__(16) char smem[27616];
    _Float16 (*sK)[40]   = (_Float16(*)[40])(smem);             // 11520
    _Float16 (*sVT)[168] = (_Float16(*)[168])(smem + 11520);    // 10752
    _Float16* sBias      = (_Float16*)(smem + 22272);           // 18*148*2 = 5328

    const int bh = blockIdx.x;
    const int b  = bh / 12;
    const int h  = bh - b * 12;
    const int t  = threadIdx.x;
    const int w    = t >> 6;        // 0..8 : q-tile index
    const int lane = t & 63;
    const int quad = lane >> 4;
    const int l15  = lane & 15;

    const int s_tile = b >> 5;
    const int i1     = b & 31;

    // --- phase 1: loads ---
    const _Float16* qg = ws16 + QH + (size_t)bh * 4608;
    const _Float16* kg = ws16 + KH + (size_t)bh * 4608;
    const _Float16* vg = ws16 + VH + (size_t)bh * 4608;

    half8 aq = *(const half8*)&qg[(size_t)(16 * w + l15) * 32 + quad * 8];

    {   // K: one uint4 per thread (144 rows x 4 chunks = 576)
        int row = t >> 2, ko = (t & 3) * 8;
        *(uint4*)&sK[row][ko] = *(const uint4*)&kg[row * 32 + ko];
    }
    for (int i = t; i < 2304; i += 576) {          // V -> V^T (chunk-XOR swizzled)
        unsigned int u = ((const unsigned int*)vg)[i];
        int m  = i >> 4, d0 = (i & 15) * 2;
        int mp = m ^ ((d0 >> 3) << 3);             // d0 even: d0,d0+1 share d0>>3
        sVT[d0][mp]     = ((const _Float16*)&u)[0];
        sVT[d0 + 1][mp] = ((const _Float16*)&u)[1];
    }
    if (t < 512) {                                 // V^T zero-pad cols 144..159
        int d = t & 31, m = 144 + (t >> 5);
        sVT[d][m ^ ((d >> 3) << 3)] = (_Float16)0;
    }
    if (bias_pre) {                                // contiguous precomputed bias
        const _Float16* bg = bias_pre + (size_t)bh * 2592;
        for (int i2 = t; i2 < 648; i2 += 576) {
            uint2 wv = *(const uint2*)&bg[i2 * 4];
            int r18 = i2 / 36;
            int col = i2 * 4 - r18 * 144;
            *(uint2*)&sBias[r18 * 148 + col] = wv;
        }
    } else {                                       // fallback: gather (padded rows)
        for (int i = t; i < 2592; i += 576) {
            int row = pidx[8 * i + s_tile];
            int r18 = i / 144;
            sBias[r18 * 148 + (i - r18 * 144)] =
                (_Float16)table[(size_t)row * 384 + i1 * 12 + h];
        }
    }
    __syncthreads();   // the ONLY barrier

    // --- phase 2: T_j = S^T tiles = mfma(K_j, Q_w) ---
    f32x4 tj[9] = {};
#pragma unroll
    for (int j = 0; j < 9; ++j) {
        half8 bk = *(const half8*)&sK[16 * j + l15][quad * 8];
        tj[j] = __builtin_amdgcn_mfma_f32_16x16x32_f16(bk, aq, tj[j], 0, 0, 0);
    }

    // --- phase 3: bias + mask + softmax over each query column ---
    const int q    = 16 * w + l15;                 // this lane's query row
    const int nb18 = q % 18;
    const _Float16* mrow = mask16 + (size_t)(b & 7) * NQQ + (size_t)q * 144 + 4 * quad;
    uint2 mz[9];
#pragma unroll
    for (int j = 0; j < 9; ++j) mz[j] = *(const uint2*)&mrow[16 * j];
#pragma unroll
    for (int j = 0; j < 9; ++j) {
        uint2 bz = *(const uint2*)&sBias[nb18 * 148 + 16 * j + 4 * quad];
        const _Float16* bb = (const _Float16*)&bz;
        const _Float16* mm = (const _Float16*)&mz[j];
#pragma unroll
        for (int reg = 0; reg < 4; ++reg)
            tj[j][reg] += (float)bb[reg] + (float)mm[reg];
    }
    float rmax = tj[0][0];
#pragma unroll
    for (int j = 0; j < 9; ++j)
#pragma unroll
        for (int reg = 0; reg < 4; ++reg) rmax = fmaxf(rmax, tj[j][reg]);
    rmax = fmaxf(rmax, __shfl_xor(rmax, 16));
    rmax = fmaxf(rmax, __shfl_xor(rmax, 32));
    float rsum = 0.0f;
#pragma unroll
    for (int j = 0; j < 9; ++j)
#pragma unroll
        for (int reg = 0; reg < 4; ++reg) {
            tj[j][reg] = __expf(tj[j][reg] - rmax);
            rsum += tj[j][reg];
        }
    rsum += __shfl_xor(rsum, 16);
    rsum += __shfl_xor(rsum, 32);
    const float inv = 1.0f / rsum;

    // pack P^T rows (scaled) to fp16 pairs; index 9 = zero pad (keys 144..159)
    unsigned int pkA[10], pkB[10];
    pkA[9] = 0u; pkB[9] = 0u;
#pragma unroll
    for (int j = 0; j < 9; ++j) {
        auto a2 = __builtin_amdgcn_cvt_pkrtz(tj[j][0] * inv, tj[j][1] * inv);
        auto b2 = __builtin_amdgcn_cvt_pkrtz(tj[j][2] * inv, tj[j][3] * inv);
        pkA[j] = *(unsigned int*)&a2;
        pkB[j] = *(unsigned int*)&b2;
    }

    // --- phase 4: O^T = V^T @ P^T ; P^T B-frags via cross-lane shuffles ---
    const int src_lo = 32 * (quad & 1) + l15;
    const int src_hi = src_lo + 16;
    const bool selhi = (quad >> 1) != 0;
    f32x4 o[2] = {};
#pragma unroll
    for (int kt = 0; kt < 5; ++kt) {
        const int j0 = 2 * kt, j1 = 2 * kt + 1;
        unsigned int a0l = __shfl((int)pkA[j0], src_lo);
        unsigned int a1l = __shfl((int)pkA[j1], src_lo);
        unsigned int b0l = __shfl((int)pkB[j0], src_lo);
        unsigned int b1l = __shfl((int)pkB[j1], src_lo);
        unsigned int a0h = __shfl((int)pkA[j0], src_hi);
        unsigned int a1h = __shfl((int)pkA[j1], src_hi);
        unsigned int b0h = __shfl((int)pkB[j0], src_hi);
        unsigned int b1h = __shfl((int)pkB[j1], src_hi);
        union { uint4 u4; half8 h8; } bp;
        bp.u4.x = selhi ? a1l : a0l;
        bp.u4.y = selhi ? b1l : b0l;
        bp.u4.z = selhi ? a1h : a0h;
        bp.u4.w = selhi ? b1h : b0h;
#pragma unroll
        for (int dt = 0; dt < 2; ++dt) {
            const int vrow = dt * 16 + l15;
            half8 av = *(const half8*)&sVT[vrow][(kt * 32 + quad * 8) ^ ((vrow >> 3) << 3)];
            o[dt] = __builtin_amdgcn_mfma_f32_16x16x32_f16(av, bp.h8, o[dt], 0, 0, 0);
        }
    }

    // --- stores: O^T[d][q] -> AO[b][q][h*32+d] ---
#pragma unroll
    for (int dt = 0; dt < 2; ++dt) {
        int d = dt * 16 + quad * 4;
        half4v hv;
#pragma unroll
        for (int reg = 0; reg < 4; ++reg) hv[reg] = (_Float16)o[dt][reg];
        *(half4v*)&AO[((size_t)b * 144 + q) * 384 + h * 32 + d] = hv;
    }
}

// ---------------------------------------------------------------------------
// K3: out = AO @ WoT^T + b_out. fp32 output. Same v2 staging as K1.
// ---------------------------------------------------------------------------
__launch_bounds__(256)
__global__ void k_out_gemm_mfma(const _Float16* __restrict__ A16,
                                const _Float16* __restrict__ WoT,
                                const float* __restrict__ bo,
                                float* __restrict__ out) {
    __shared__ __align__(16) _Float16 sA[128 * 64];
    __shared__ __align__(16) _Float16 sB[128 * 64];
    const int t    = threadIdx.x;
    const int lane = t & 63;
    const int w    = t >> 6;
    const int quad = lane >> 4;
    const int l15  = lane & 15;
    // bijective XCD swizzle: 864 = 8 * 108; col-tile fastest within chunk
    const int bid = blockIdx.x;
    const int wg  = (bid & 7) * 108 + (bid >> 3);
    const int cy  = wg % 3, rx = wg / 3;
    const int r0  = rx * 128, c0 = cy * 128;
    const int wr  = (w >> 1) * 64, wc = (w & 1) * 64;

    const int drow = t >> 3;
    const int schk = (t & 7) ^ (drow & 7);
    const _Float16* gA = &A16[(size_t)(r0 + drow) * 384 + schk * 8];
    const _Float16* gB = &WoT[(size_t)(c0 + drow) * 384 + schk * 8];
    char* lA = (char*)sA + t * 16;
    char* lB = (char*)sB + t * 16;

    const int x7 = l15 & 7;
    const char* rA = (const char*)sA + (wr + l15) * 128;
    const char* rB = (const char*)sB + (wc + l15) * 128;

    f32x4 acc[4][4] = {};

    for (int kk = 0; kk < 384; kk += 64) {
#pragma unroll
        for (int j = 0; j < 4; ++j) {
            GLD16(gA + (size_t)j * 12288 + kk, lA + j * 4096);
            GLD16(gB + (size_t)j * 12288 + kk, lB + j * 4096);
        }
        __syncthreads();
#pragma unroll
        for (int s = 0; s < 2; ++s) {
            const int ca = (((s * 4 + quad) ^ x7) << 4);
            half8 a[4], b[4];
#pragma unroll
            for (int i = 0; i < 4; ++i) a[i] = *(const half8*)(rA + i * 2048 + ca);
#pragma unroll
            for (int j = 0; j < 4; ++j) b[j] = *(const half8*)(rB + j * 2048 + ca);
#pragma unroll
            for (int i = 0; i < 4; ++i)
#pragma unroll
                for (int j = 0; j < 4; ++j)
                    acc[i][j] = __builtin_amdgcn_mfma_f32_16x16x32_f16(a[i], b[j], acc[i][j], 0, 0, 0);
        }
        __syncthreads();
    }

#pragma unroll
    for (int j = 0; j < 4; ++j) {
        int c = c0 + wc + 16 * j + l15;
        float bias = bo[c];
#pragma unroll
        for (int i = 0; i < 4; ++i) {
#pragma unroll
            for (int reg = 0; reg < 4; ++reg) {
                int r = r0 + wr + 16 * i + quad * 4 + reg;
                out[(size_t)r * 384 + c] = acc[i][j][reg] + bias;
            }
        }
    }
}

// ---------------------------------------------------------------------------
extern "C" void kernel_launch(void* const* d_in, const int* in_sizes, int n_in,
                              void* d_out, int out_size, void* d_ws, size_t ws_size,
                              hipStream_t stream) {
    const float* x      = (const float*)d_in[0];
    const float* mask   = (const float*)d_in[1];
    const float* w_qkv  = (const float*)d_in[2];
    const float* b_qkv  = (const float*)d_in[3];
    const float* w_out  = (const float*)d_in[4];
    const float* b_out  = (const float*)d_in[5];
    const float* table  = (const float*)d_in[6];
    const int*   pidx   = (const int*)d_in[7];
    float* out = (float*)d_out;
    _Float16* ws16 = (_Float16*)d_ws;

    const bool pre = ws_size >= (size_t)WS_NEED_BYTES;
    _Float16* bias16 = pre ? (ws16 + BIASH) : (_Float16*)nullptr;

    hipLaunchKernelGGL(k_prep,          dim3(pre ? 15426 : 14130), dim3(256), 0, stream,
                       x, ws16 + X16H, w_qkv, ws16 + WTH, w_out, ws16 + WOTH,
                       mask, ws16 + MASKH, table, pidx, bias16);
    hipLaunchKernelGGL(k_qkv_gemm_mfma, dim3(2592), dim3(256), 0, stream,
                       ws16 + X16H, ws16 + WTH, b_qkv, ws16);
    hipLaunchKernelGGL(k_attn_fused_mfma, dim3(3072), dim3(576), 0, stream,
                       ws16, ws16 + MASKH, table, pidx, bias16, ws16 + AOH);
    hipLaunchKernelGGL(k_out_gemm_mfma, dim3(864), dim3(256), 0, stream,
                       ws16 + AOH, ws16 + WOTH, b_out, out);
}